// Round 4
// baseline (7442.843 us; speedup 1.0000x reference)
//
#include <hip/hip_runtime.h>
#include <hip/hip_fp16.h>

#define BB 64
#define SS 1024
#define HD 256
#define GG 768   // 3*HD
#define NT 256   // 4 waves/block, 1 wave/SIMD -> full 512-reg unified file per wave

typedef _Float16 v8h __attribute__((ext_vector_type(8)));
typedef float v4f __attribute__((ext_vector_type(4)));

#define MFMA_F16(a, b, c) __builtin_amdgcn_mfma_f32_16x16x32_f16((a), (b), (c), 0, 0, 0)

__device__ __forceinline__ float sigm(float x) {
    return 1.0f / (1.0f + __expf(-x));
}
__device__ __forceinline__ float tanh_fast(float x) {
    float e = __expf(2.0f * fabsf(x));
    float t = 1.0f - 2.0f / (e + 1.0f);
    return copysignf(t, x);
}

// ---------------------------------------------------------------------------
// Tile conventions (48 N-tiles over the 768 gate rows; tile t covers W rows
// (t>>4)*256 + (t&15)*16 .. +16):
//   B-frag (K=32 x N=16) for tile t, k-block kk: lane l holds
//     W[(t>>4)*256+(t&15)*16+(l&15)][kk*32+(l>>4)*8+j], j=0..7
//   A-frag (M=16 x K=32): lane l holds A[l&15][kk*32+(l>>4)*8+j]
//   C-frag (verified m89/m91): lane l, reg q -> col=l&15, row=(l>>4)*4+q
// A/B use the same k-enumeration -> result correct independent of hw k-order.
// ---------------------------------------------------------------------------
__device__ __forceinline__ v8h load_bfrag(const float* W, int tile, int kk, int l) {
    int n  = ((tile >> 4) << 8) + ((tile & 15) << 4) + (l & 15);
    int k0 = (kk << 5) + ((l >> 4) << 3);
    const float4* p = (const float4*)(W + (size_t)n * 256 + k0);
    float4 f0 = p[0], f1 = p[1];
    v8h r;
    r[0] = (_Float16)f0.x; r[1] = (_Float16)f0.y; r[2] = (_Float16)f0.z; r[3] = (_Float16)f0.w;
    r[4] = (_Float16)f1.x; r[5] = (_Float16)f1.y; r[6] = (_Float16)f1.z; r[7] = (_Float16)f1.w;
    return r;
}

// LDS f16 matrix [16 rows][256 k], byte(row,k) = (row*512 + k*2) ^ ((row&7)<<4)
// XOR swizzle spreads the 16-lane column read across all banks (T2 pattern).
__device__ __forceinline__ v8h read_afrag(const char* base, int kk, int l) {
    int row = l & 15;
    int off = row * 512 + (kk << 6) + ((l >> 4) << 4);
    off ^= (row & 7) << 4;
    return *(const v8h*)(base + off);
}

__device__ __forceinline__ void cvt_store16(char* dst, int sbase, int swz,
                                            float4 f0, float4 f1, float4 f2, float4 f3) {
    v8h a, b;
    a[0] = (_Float16)f0.x; a[1] = (_Float16)f0.y; a[2] = (_Float16)f0.z; a[3] = (_Float16)f0.w;
    a[4] = (_Float16)f1.x; a[5] = (_Float16)f1.y; a[6] = (_Float16)f1.z; a[7] = (_Float16)f1.w;
    b[0] = (_Float16)f2.x; b[1] = (_Float16)f2.y; b[2] = (_Float16)f2.z; b[3] = (_Float16)f2.w;
    b[4] = (_Float16)f3.x; b[5] = (_Float16)f3.y; b[6] = (_Float16)f3.z; b[7] = (_Float16)f3.w;
    *(v8h*)(dst + ((sbase + 0) ^ swz)) = a;
    *(v8h*)(dst + ((sbase + 16) ^ swz)) = b;
}

// producer/consumer flags: per-(role,bg) monotone chunk counters, 64B-padded
__device__ __forceinline__ void wait_ge(unsigned* f, unsigned v) {
    if (threadIdx.x == 0) {
        while (__hip_atomic_load(f, __ATOMIC_RELAXED, __HIP_MEMORY_SCOPE_AGENT) < v)
            __builtin_amdgcn_s_sleep(2);
        (void)__hip_atomic_load(f, __ATOMIC_ACQUIRE, __HIP_MEMORY_SCOPE_AGENT);
    }
    __syncthreads();
}
__device__ __forceinline__ void publish(unsigned* f, unsigned v) {
    __syncthreads();   // each wave drains its vmcnt before s_barrier
    if (threadIdx.x == 0)
        __hip_atomic_store(f, v, __ATOMIC_RELEASE, __HIP_MEMORY_SCOPE_AGENT);
}

// ---------------------------------------------------------------------------
// MFMA pipeline: 16 blocks = 4 roles x 4 batch-groups (16 batches each).
// role 0: P0 GEMM  X->xg0 ring        role 2: R0 recurrence (16 batches) -> h1
// role 1: P1 GEMM h1->xg1 ring        role 3: R1 recurrence -> h2 (+cat)
// Weights live in the unified VGPR/AGPR file as MFMA B-fragments (384 regs) --
// consumed DIRECTLY by v_mfma (no accvgpr moves, no spill streaming).
// Ring layout is fragment-order: [bg][slot][tt][tile(48)][lane(64)][q(4)] f32,
// so producer stores and rec loads are coalesced dwordx4.
// ---------------------------------------------------------------------------
__global__ __launch_bounds__(NT, 1) void gru_pipe(
    const float* __restrict__ X,
    const float* __restrict__ Wih0, const float* __restrict__ bih0,
    const float* __restrict__ Whh0, const float* __restrict__ bhh0,
    const float* __restrict__ Wih1, const float* __restrict__ bih1,
    const float* __restrict__ Whh1, const float* __restrict__ bhh1,
    float* __restrict__ h2out, float* __restrict__ cat,
    float* __restrict__ ring0, float* __restrict__ ring1,
    unsigned* __restrict__ prog, int CT, int NS, int NC)
{
    __shared__ __align__(16) char lds[16384];   // 2 x 8KB ping-pong (A-stage / h-state)

    const int role = blockIdx.x >> 2;
    const int bg   = blockIdx.x & 3;
    const int g    = threadIdx.x;
    const int wv   = g >> 6;
    const int l    = g & 63;
    const int lo   = l & 15;
    const int grp  = l >> 4;

    unsigned* f_p0 = prog + (0 * 4 + bg) * 16;
    unsigned* f_p1 = prog + (1 * 4 + bg) * 16;
    unsigned* f_r0 = prog + (2 * 4 + bg) * 16;
    unsigned* f_r1 = prog + (3 * 4 + bg) * 16;

    v8h wB[12][8];   // 12 tiles x 8 k-blocks = 384 regs of weights (AGPR-resident)

    if (role <= 1) {
        // ------- projection producer (GEMM over 16 batches x CT timesteps) -------
        const float* Wp   = (role == 0) ? Wih0 : Wih1;
        const float* bi   = (role == 0) ? bih0 : bih1;
        const float* bh   = (role == 0) ? bhh0 : bhh1;   // fold hidden bias for r,z
        const float* Xs   = (role == 0) ? X : cat;
        const int xstride = (role == 0) ? 256 : 512;
        float* ringo      = (role == 0) ? ring0 : ring1;
        unsigned* f_up    = (role == 0) ? nullptr : f_r0;
        unsigned* f_cons  = (role == 0) ? f_r0 : f_r1;
        unsigned* f_out   = (role == 0) ? f_p0 : f_p1;

        float bias[12];
#pragma unroll
        for (int t12 = 0; t12 < 12; t12++) {
            int tile = wv * 12 + t12;
            int n = ((tile >> 4) << 8) + ((tile & 15) << 4) + lo;
            bias[t12] = bi[n] + (tile < 32 ? bh[n] : 0.0f);
#pragma unroll
            for (int kk = 0; kk < 8; kk++) wB[t12][kk] = load_bfrag(Wp, tile, kk, l);
        }

        const int srow  = g >> 4;            // staging row (batch-within-group)
        const int scol  = (g & 15) << 4;     // k-chunk base (16 floats)
        const int swz   = (srow & 7) << 4;
        const int sbase = srow * 512 + ((g & 15) << 5);
        const size_t srowbase = (size_t)(bg * 16 + srow) * SS;

        for (int c = 0; c < NC; c++) {
            if (f_up) wait_ge(f_up, c + 1);
            if (c >= NS) wait_ge(f_cons, c - NS + 1);
            {   // stage tt=0 synchronously
                const float* src = Xs + (srowbase + (size_t)c * CT) * xstride + scol;
                cvt_store16(lds, sbase, swz,
                            ((const float4*)src)[0], ((const float4*)src)[1],
                            ((const float4*)src)[2], ((const float4*)src)[3]);
            }
            __syncthreads();
            float* ringc = ringo + ((size_t)(bg * NS + (c % NS)) * CT) * 12288;
            for (int tt = 0; tt < CT; tt++) {
                // T14: issue next tile's global loads BEFORE compute, write after
                float4 f0, f1, f2, f3;
                const bool pre = (tt + 1 < CT);
                if (pre) {
                    const float* src = Xs + (srowbase + (size_t)(c * CT + tt + 1)) * xstride + scol;
                    f0 = ((const float4*)src)[0]; f1 = ((const float4*)src)[1];
                    f2 = ((const float4*)src)[2]; f3 = ((const float4*)src)[3];
                }
                const char* abuf = lds + ((tt & 1) << 13);
                v4f acc[12];
#pragma unroll
                for (int t12 = 0; t12 < 12; t12++) {
                    float bv = bias[t12];
                    acc[t12] = (v4f){bv, bv, bv, bv};
                }
                v8h Aa = read_afrag(abuf, 0, l), Ab = read_afrag(abuf, 1, l);
#pragma unroll
                for (int kk = 0; kk < 8; kk++) {
                    v8h Ac = (kk & 1) ? Ab : Aa;
#pragma unroll
                    for (int t12 = 0; t12 < 12; t12++)
                        acc[t12] = MFMA_F16(Ac, wB[t12][kk], acc[t12]);
                    if (kk + 2 < 8) {
                        if (kk & 1) Ab = read_afrag(abuf, kk + 2, l);
                        else        Aa = read_afrag(abuf, kk + 2, l);
                    }
                }
                if (pre)   // loads landed under the MFMA phase
                    cvt_store16(lds + (((tt + 1) & 1) << 13), sbase, swz, f0, f1, f2, f3);
                v4f* rp = (v4f*)(ringc + (size_t)tt * 12288);
#pragma unroll
                for (int t12 = 0; t12 < 12; t12++) rp[(wv * 12 + t12) * 64 + l] = acc[t12];
                __syncthreads();
            }
            publish(f_out, c + 1);
        }
    } else {
        // ------- recurrence: 16 batches simultaneously, M=16 MFMA tiles -------
        const float* Wp    = (role == 2) ? Whh0 : Whh1;
        const float* bh    = (role == 2) ? bhh0 : bhh1;
        const float* ringi = (role == 2) ? ring0 : ring1;
        unsigned* f_in  = (role == 2) ? f_p0 : f_p1;
        unsigned* f_out = (role == 2) ? f_r0 : f_r1;
        float* outA   = (role == 2) ? cat : h2out;
        int   strideA = (role == 2) ? 512 : 256;
        float* outB   = (role == 2) ? nullptr : (cat + 256);   // stride 512

        // wave wv owns hidden cols [wv*64, wv*64+64) for ALL 3 gates ->
        // gate combine is lane-local. t12: 0-3=r, 4-7=z, 8-11=n subtiles.
#pragma unroll
        for (int t12 = 0; t12 < 12; t12++) {
            int tile = ((t12 >> 2) << 4) + wv * 4 + (t12 & 3);
#pragma unroll
            for (int kk = 0; kk < 8; kk++) wB[t12][kk] = load_bfrag(Wp, tile, kk, l);
        }
        float bn[4];
#pragma unroll
        for (int sub = 0; sub < 4; sub++) bn[sub] = bh[512 + wv * 64 + sub * 16 + lo];

        // zero h buffer 0 (h(0)=0; zeros are swizzle-invariant) — 8KB
        ((float4*)lds)[g]       = (float4){0.f, 0.f, 0.f, 0.f};
        ((float4*)lds)[g + 256] = (float4){0.f, 0.f, 0.f, 0.f};
        __syncthreads();

        float hp[4][4];
#pragma unroll
        for (int s = 0; s < 4; s++)
#pragma unroll
            for (int q = 0; q < 4; q++) hp[s][q] = 0.0f;

        v4f aR[4], aZ[4], aN[4], xnv[4];

        for (int c = 0; c < NC; c++) {
            wait_ge(f_in, c + 1);
            const float* ringc = ringi + ((size_t)(bg * NS + (c % NS)) * CT) * 12288;
            {   // load xg fragments for tt=0
                const v4f* rp = (const v4f*)ringc;
#pragma unroll
                for (int sub = 0; sub < 4; sub++) {
                    aR[sub]  = rp[(wv * 4 + sub) * 64 + l];
                    aZ[sub]  = rp[(16 + wv * 4 + sub) * 64 + l];
                    xnv[sub] = rp[(32 + wv * 4 + sub) * 64 + l];
                    float bv = bn[sub];
                    aN[sub] = (v4f){bv, bv, bv, bv};
                }
            }
            for (int tt = 0; tt < CT; tt++) {
                const int t = c * CT + tt;
                const char* hbuf = lds + ((t & 1) << 13);        // h(t)
                char* hbufn      = lds + (((t + 1) & 1) << 13);  // h(t+1)

                v8h Aa = read_afrag(hbuf, 0, l), Ab = read_afrag(hbuf, 1, l);
#pragma unroll
                for (int kk = 0; kk < 8; kk++) {
                    v8h Ac = (kk & 1) ? Ab : Aa;
#pragma unroll
                    for (int s = 0; s < 4; s++) aR[s] = MFMA_F16(Ac, wB[s][kk], aR[s]);
#pragma unroll
                    for (int s = 0; s < 4; s++) aZ[s] = MFMA_F16(Ac, wB[4 + s][kk], aZ[s]);
#pragma unroll
                    for (int s = 0; s < 4; s++) aN[s] = MFMA_F16(Ac, wB[8 + s][kk], aN[s]);
                    if (kk + 2 < 8) {
                        if (kk & 1) Ab = read_afrag(hbuf, kk + 2, l);
                        else        Aa = read_afrag(hbuf, kk + 2, l);
                    }
                }
                // gate epilogue: lane-local (r,z,n aligned by tile ownership)
#pragma unroll
                for (int sub = 0; sub < 4; sub++)
#pragma unroll
                    for (int q = 0; q < 4; q++) {
                        float r = sigm(aR[sub][q]);
                        float z = sigm(aZ[sub][q]);
                        float n = tanh_fast(xnv[sub][q] + r * aN[sub][q]);
                        hp[sub][q] = (1.0f - z) * n + z * hp[sub][q];
                    }
                // prefetch next step's xg fragments (acc regs now dead)
                if (tt + 1 < CT) {
                    const v4f* rp = (const v4f*)(ringc + (size_t)(tt + 1) * 12288);
#pragma unroll
                    for (int sub = 0; sub < 4; sub++) {
                        aR[sub]  = rp[(wv * 4 + sub) * 64 + l];
                        aZ[sub]  = rp[(16 + wv * 4 + sub) * 64 + l];
                        xnv[sub] = rp[(32 + wv * 4 + sub) * 64 + l];
                        float bv = bn[sub];
                        aN[sub] = (v4f){bv, bv, bv, bv};
                    }
                }
                // write h(t+1) to LDS (f16, swizzled) + global outputs (f32)
#pragma unroll
                for (int sub = 0; sub < 4; sub++) {
                    int col = wv * 64 + sub * 16 + lo;
#pragma unroll
                    for (int q = 0; q < 4; q++) {
                        int row = grp * 4 + q;
                        float h = hp[sub][q];
                        *(_Float16*)(hbufn + ((row * 512 + col * 2) ^ ((row & 7) << 4))) =
                            (_Float16)h;
                        size_t gb = (size_t)(bg * 16 + row) * SS + t;
                        outA[gb * strideA + col] = h;
                        if (outB) outB[gb * 512 + col] = h;
                    }
                }
                __syncthreads();
            }
            publish(f_out, c + 1);
        }
    }
}

// ---------------------------------------------------------------------------
extern "C" void kernel_launch(void* const* d_in, const int* in_sizes, int n_in,
                              void* d_out, int out_size, void* d_ws, size_t ws_size,
                              hipStream_t stream)
{
    const float* inputs = (const float*)d_in[0];
    const float* W_ih0  = (const float*)d_in[1];
    const float* W_hh0  = (const float*)d_in[2];
    const float* b_ih0  = (const float*)d_in[3];
    const float* b_hh0  = (const float*)d_in[4];
    const float* W_ih1  = (const float*)d_in[5];
    const float* W_hh1  = (const float*)d_in[6];
    const float* b_ih1  = (const float*)d_in[7];
    const float* b_hh1  = (const float*)d_in[8];

    float* h2out = (float*)d_out;                    // [B,S,256]
    float* cat   = h2out + (size_t)BB * SS * HD;     // [B,S,512] = [h1 | h2]

    unsigned char* ws = (unsigned char*)d_ws;
    unsigned* prog = (unsigned*)ws;
    const size_t FLAG_BYTES = 4 * 64 * 16 * sizeof(unsigned);
    size_t avail = ws_size > FLAG_BYTES ? ws_size - FLAG_BYTES : 0;

    // pick chunk length CT and ring slots NS to fit workspace
    int CT = 64, NS = 0;
    for (;;) {
        size_t slot = (size_t)BB * CT * GG * sizeof(float);   // = 4bg x CT x 12288 floats
        size_t m = slot ? avail / (2 * slot) : 0;
        int nc = SS / CT;
        NS = (int)(m < (size_t)nc ? m : (size_t)nc);
        if (NS >= 2 || CT == 8) break;
        CT >>= 1;
    }
    if (NS < 1) NS = 1;
    int NC = SS / CT;

    float* ring0 = (float*)(ws + FLAG_BYTES);
    float* ring1 = ring0 + (size_t)BB * NS * CT * GG;

    hipMemsetAsync(prog, 0, FLAG_BYTES, stream);
    gru_pipe<<<16, NT, 0, stream>>>(inputs,
                                    W_ih0, b_ih0, W_hh0, b_hh0,
                                    W_ih1, b_ih1, W_hh1, b_hh1,
                                    h2out, cat, ring0, ring1, prog, CT, NS, NC);
}

// Round 5
// 1695.165 us; speedup vs baseline: 4.3906x; 4.3906x over previous
//
#include <hip/hip_runtime.h>
#include <hip/hip_fp16.h>

#define BB 64
#define SS 1024
#define HD 256
#define GG 768   // 3*HD
#define NT 512   // 8 waves = 2 waves/SIMD -> 256-VGPR cap; weights (192) + working (~30) fit

typedef _Float16 h2_t __attribute__((ext_vector_type(2)));
typedef _Float16 h4_t __attribute__((ext_vector_type(4)));
typedef _Float16 h8_t __attribute__((ext_vector_type(8)));

#define FDOT2(a, b, c) __builtin_amdgcn_fdot2((a), (b), (c), false)

__device__ __forceinline__ float sigm(float x) {
    return 1.0f / (1.0f + __expf(-x));
}
__device__ __forceinline__ float tanh_fast(float x) {
    float e = __expf(2.0f * fabsf(x));
    float t = 1.0f - 2.0f / (e + 1.0f);
    return copysignf(t, x);
}

// DPP pair butterfly: add the partner K-half partial (lane ^ 1). Both lanes get the
// full sum (identical IEEE result in both). Pure VALU, no LDS.
__device__ __forceinline__ float pair_reduce(float x) {
    int t = __builtin_amdgcn_update_dpp(0, __float_as_int(x), 0xB1, 0xF, 0xF, true); // quad_perm [1,0,3,2]
    return x + __int_as_float(t);
}

// One weight row half: 128 f32 -> 64 packed f16 pairs (64 VGPRs), statically indexed.
__device__ __forceinline__ void load_wrow_half(const float* W, int row, int sl, h2_t wreg[64]) {
    const float2* p = (const float2*)(W + (size_t)row * 256 + sl * 128);
#pragma unroll
    for (int k = 0; k < 64; k++) {
        float2 f = p[k];
        h2_t q; q.x = (_Float16)f.x; q.y = (_Float16)f.y;
        wreg[k] = q;
    }
}

// 3-gate partial dot over this lane's 128-elem K-half. 16 ds_read_b128 (wave sees
// only 2 distinct addresses -> pure broadcast, conflict-free), 192 fdot2 in 3 chains.
__device__ __forceinline__ void dot3(const char* base, const h2_t w0[64], const h2_t w1[64],
                                     const h2_t w2[64], float& a0, float& a1, float& a2) {
#pragma unroll
    for (int j = 0; j < 16; j++) {
        h8_t v = *(const h8_t*)(base + j * 16);
        h2_t p0, p1, p2, p3;
        p0.x = v[0]; p0.y = v[1];
        p1.x = v[2]; p1.y = v[3];
        p2.x = v[4]; p2.y = v[5];
        p3.x = v[6]; p3.y = v[7];
        a0 = FDOT2(w0[4 * j + 0], p0, a0); a0 = FDOT2(w0[4 * j + 1], p1, a0);
        a0 = FDOT2(w0[4 * j + 2], p2, a0); a0 = FDOT2(w0[4 * j + 3], p3, a0);
        a1 = FDOT2(w1[4 * j + 0], p0, a1); a1 = FDOT2(w1[4 * j + 1], p1, a1);
        a1 = FDOT2(w1[4 * j + 2], p2, a1); a1 = FDOT2(w1[4 * j + 3], p3, a1);
        a2 = FDOT2(w2[4 * j + 0], p0, a2); a2 = FDOT2(w2[4 * j + 1], p1, a2);
        a2 = FDOT2(w2[4 * j + 2], p2, a2); a2 = FDOT2(w2[4 * j + 3], p3, a2);
    }
}

// LDS-only barrier: drains ds ops, leaves global stores in flight across steps.
// (publish() below still does a full __syncthreads drain before releasing the flag.)
__device__ __forceinline__ void barrier_lds() {
    asm volatile("s_waitcnt lgkmcnt(0)\n\ts_barrier" ::: "memory");
}

// producer/consumer flags: per-(role,batch) monotone chunk counters, 64B-padded
__device__ __forceinline__ void wait_ge(unsigned* f, unsigned v) {
    if (threadIdx.x == 0) {
        while (__hip_atomic_load(f, __ATOMIC_RELAXED, __HIP_MEMORY_SCOPE_AGENT) < v)
            __builtin_amdgcn_s_sleep(2);
        (void)__hip_atomic_load(f, __ATOMIC_ACQUIRE, __HIP_MEMORY_SCOPE_AGENT);
    }
    __syncthreads();
}
__device__ __forceinline__ void publish(unsigned* f, unsigned v) {
    __syncthreads();   // drains all waves' vmcnt/lgkmcnt before the flag release
    if (threadIdx.x == 0)
        __hip_atomic_store(f, v, __ATOMIC_RELEASE, __HIP_MEMORY_SCOPE_AGENT);
}

// ---------------------------------------------------------------------------
// Persistent 4-stage pipeline: 256 blocks = 4 roles x 64 batches, 512 thr/block.
// role 0: P0  inputs -> xg0 ring          role 2: R0  xg0 -> h1 (cat)
// role 1: P1  h1(cat) -> xg1 ring         role 3: R1  xg1 -> h2 (out + cat)
// Thread (i = wv*32 + l>>1, sl = l&1) owns ALL 3 gate rows {i,256+i,512+i} over
// K-half sl: 192 weight VGPRs -- fits the 256-reg cap at 2 waves/SIMD (no spill).
// Pair-DPP completes the dot; epilogue is lane-local; h ping-pong, 1 lds-barrier/step.
// ---------------------------------------------------------------------------
__global__ __launch_bounds__(NT, 2) void gru_pipe(
    const float* __restrict__ X,
    const float* __restrict__ Wih0, const float* __restrict__ bih0,
    const float* __restrict__ Whh0, const float* __restrict__ bhh0,
    const float* __restrict__ Wih1, const float* __restrict__ bih1,
    const float* __restrict__ Whh1, const float* __restrict__ bhh1,
    float* __restrict__ h2out, float* __restrict__ cat,
    float* __restrict__ ring0, float* __restrict__ ring1,
    unsigned* __restrict__ prog, int CT, int NS, int NC)
{
    __shared__ __align__(16) char lds[32768];  // producer: CT*512B x-staging; rec: 2x512B h ping-pong

    const int role = blockIdx.x >> 6;
    const int b    = blockIdx.x & 63;
    const int g    = threadIdx.x;
    const int wv   = g >> 6;
    const int l    = g & 63;
    const int i    = wv * 32 + (l >> 1);   // owned output index in [0,256)
    const int sl   = l & 1;                // K-half

    unsigned* f_p0 = prog + (0 * 64 + b) * 16;
    unsigned* f_p1 = prog + (1 * 64 + b) * 16;
    unsigned* f_r0 = prog + (2 * 64 + b) * 16;
    unsigned* f_r1 = prog + (3 * 64 + b) * 16;

    h2_t w0[64], w1[64], w2[64];   // 192 regs: rows i / 256+i / 512+i, K-half sl

    if (role <= 1) {
        // ------- projection producer -------
        const float* Wp   = (role == 0) ? Wih0 : Wih1;
        const float* bp   = (role == 0) ? bih0 : bih1;
        const float* Xs   = (role == 0) ? X : cat;
        const int xstride = (role == 0) ? 256 : 512;
        float* ringo      = (role == 0) ? ring0 : ring1;
        unsigned* f_up    = (role == 0) ? nullptr : f_r0;   // P1 waits for h1 chunk
        unsigned* f_cons  = (role == 0) ? f_r0 : f_r1;      // ring reuse guard
        unsigned* f_out   = (role == 0) ? f_p0 : f_p1;

        load_wrow_half(Wp, i, sl, w0);
        load_wrow_half(Wp, 256 + i, sl, w1);
        load_wrow_half(Wp, 512 + i, sl, w2);
        const float b0 = bp[i], b1 = bp[256 + i], b2 = bp[512 + i];
        char* xb = (char*)lds;

        for (int c = 0; c < NC; c++) {
            if (f_up) wait_ge(f_up, c + 1);
            if (c >= NS) wait_ge(f_cons, c - NS + 1);
            const int t0 = c * CT;
            // stage CT x-vectors as f16 (coalesced float4 loads, 8B packed stores)
            for (int idx4 = g; idx4 < CT * 64; idx4 += NT) {
                int tt = idx4 >> 6, k4 = idx4 & 63;
                const float4* src = (const float4*)(Xs + ((size_t)b * SS + t0 + tt) * xstride);
                float4 f = src[k4];
                h4_t q;
                q[0] = (_Float16)f.x; q[1] = (_Float16)f.y;
                q[2] = (_Float16)f.z; q[3] = (_Float16)f.w;
                *(h4_t*)(xb + tt * 512 + k4 * 8) = q;
            }
            __syncthreads();
            float* ringc = ringo + ((size_t)b * NS + (c % NS)) * ((size_t)CT * GG);
            for (int tt = 0; tt < CT; tt++) {
                float a0 = 0.f, a1 = 0.f, a2 = 0.f;
                dot3(xb + tt * 512 + sl * 256, w0, w1, w2, a0, a1, a2);
                float pr = pair_reduce(a0) + b0;
                float pz = pair_reduce(a1) + b1;
                float pn = pair_reduce(a2) + b2;
                float* rt = ringc + (size_t)tt * GG;
                if (sl == 0) { rt[i] = pr; rt[256 + i] = pz; }
                else         { rt[512 + i] = pn; }
            }
            publish(f_out, c + 1);   // its syncthreads also guards LDS reuse
        }
    } else {
        // ------- recurrence -------
        const float* Wp    = (role == 2) ? Whh0 : Whh1;
        const float* bp    = (role == 2) ? bhh0 : bhh1;
        const float* ringi = (role == 2) ? ring0 : ring1;
        unsigned* f_in  = (role == 2) ? f_p0 : f_p1;
        unsigned* f_out = (role == 2) ? f_r0 : f_r1;

        load_wrow_half(Wp, i, sl, w0);
        load_wrow_half(Wp, 256 + i, sl, w1);
        load_wrow_half(Wp, 512 + i, sl, w2);
        const float b0 = bp[i], b1 = bp[256 + i], b2 = bp[512 + i];
        char* xb = (char*)lds;

        // zero h buffer 0 (h(0) = 0): 512B = 128 floats
        if (g < 128) ((float*)xb)[g] = 0.0f;
        __syncthreads();
        float hp = 0.0f;

        for (int c = 0; c < NC; c++) {
            wait_ge(f_in, c + 1);
            const float* ringc = ringi + ((size_t)b * NS + (c % NS)) * ((size_t)CT * GG);
            for (int tt = 0; tt < CT; tt++) {
                const int t = c * CT + tt;
                const char* hb = xb + ((t & 1) << 9);         // h(t)
                char* hbn      = xb + (((t + 1) & 1) << 9);   // h(t+1)
                // issue this step's xg loads early; latency hides under the dot
                const float* xgp = ringc + (size_t)tt * GG;
                float xr = xgp[i], xz = xgp[256 + i], xn = xgp[512 + i];
                float a0 = 0.f, a1 = 0.f, a2 = 0.f;
                dot3(hb + sl * 256, w0, w1, w2, a0, a1, a2);
                float hr = pair_reduce(a0) + b0;
                float hz = pair_reduce(a1) + b1;
                float hn = pair_reduce(a2) + b2;
                float rg = sigm(xr + hr);
                float zg = sigm(xz + hz);
                float ng = tanh_fast(xn + rg * hn);
                float hnew = (1.0f - zg) * ng + zg * hp;
                hp = hnew;
                if (sl == 0) *(_Float16*)(hbn + i * 2) = (_Float16)hnew;  // f16 h for next dot
                size_t tb = (size_t)b * SS + t;
                if (role == 2) {
                    if (sl) cat[tb * 512 + i] = hnew;                    // h1 -> cat[:,:,0:256]
                } else {
                    if (sl) h2out[tb * 256 + i] = hnew;                  // h2 -> output
                    else    cat[tb * 512 + 256 + i] = hnew;              // h2 -> cat[:,:,256:512]
                }
                barrier_lds();   // LDS-only drain; global stores stay in flight
            }
            publish(f_out, c + 1);
        }
    }
}

// ---------------------------------------------------------------------------
extern "C" void kernel_launch(void* const* d_in, const int* in_sizes, int n_in,
                              void* d_out, int out_size, void* d_ws, size_t ws_size,
                              hipStream_t stream)
{
    const float* inputs = (const float*)d_in[0];
    const float* W_ih0  = (const float*)d_in[1];
    const float* W_hh0  = (const float*)d_in[2];
    const float* b_ih0  = (const float*)d_in[3];
    const float* b_hh0  = (const float*)d_in[4];
    const float* W_ih1  = (const float*)d_in[5];
    const float* W_hh1  = (const float*)d_in[6];
    const float* b_ih1  = (const float*)d_in[7];
    const float* b_hh1  = (const float*)d_in[8];

    float* h2out = (float*)d_out;                    // [B,S,256]
    float* cat   = h2out + (size_t)BB * SS * HD;     // [B,S,512] = [h1 | h2]

    unsigned char* ws = (unsigned char*)d_ws;
    unsigned* prog = (unsigned*)ws;
    const size_t FLAG_BYTES = 4 * 64 * 16 * sizeof(unsigned);   // 64B-padded counters
    size_t avail = ws_size > FLAG_BYTES ? ws_size - FLAG_BYTES : 0;

    // pick chunk length CT and ring slots NS to fit workspace
    int CT = 64, NS = 0;
    for (;;) {
        size_t slot = (size_t)BB * CT * GG * sizeof(float);   // one slot, one ring
        size_t m = slot ? avail / (2 * slot) : 0;
        int nc = SS / CT;
        NS = (int)(m < (size_t)nc ? m : (size_t)nc);
        if (NS >= 2 || CT == 8) break;
        CT >>= 1;
    }
    if (NS < 1) NS = 1;
    int NC = SS / CT;

    float* ring0 = (float*)(ws + FLAG_BYTES);
    float* ring1 = ring0 + (size_t)BB * NS * CT * GG;

    hipMemsetAsync(prog, 0, FLAG_BYTES, stream);
    gru_pipe<<<256, NT, 0, stream>>>(inputs,
                                     W_ih0, b_ih0, W_hh0, b_hh0,
                                     W_ih1, b_ih1, W_hh1, b_hh1,
                                     h2out, cat, ring0, ring1, prog, CT, NS, NC);
}